// Round 3
// baseline (329.745 us; speedup 1.0000x reference)
//
#include <hip/hip_runtime.h>
#include <stdint.h>

// GatedLSTM — fp32 I/O (reference dtypes are float32), multi-launch, no device-scope sync.
// 13x k_char(t): software-pipelined char LSTM (layer1@t + layer2@t-1), h through ws
// across kernel boundaries; cell states block-exclusive. Then k_mix (char outputs +
// cte@c2), k_word(0), k_word(1), k_dec (50000x512 matvec).

static __device__ __forceinline__ float dot4(float4 w, const float* p){
    return w.x*p[0] + w.y*p[1] + w.z*p[2] + w.w*p[3];
}
static __device__ __forceinline__ float sigf(float x){ return 1.0f / (1.0f + __expf(-x)); }
static __device__ __forceinline__ float tanhf_(float x){
    x = fminf(fmaxf(x, -15.0f), 15.0f);
    float e = __expf(2.0f * x);
    return (e - 1.0f) / (e + 1.0f);
}

// ws layout (floats):
//   0    : h1 double buffer [2][256]   (char layer0 hidden)
//   512  : h2 double buffer [2][256]   (char layer1 hidden)
//   1024 : c1 [256]   (block-exclusive)
//   1280 : c2 [256]   (block-exclusive)
//   1536 : xcw [512]  (char_to_embedding @ c2)
//   2048 : hw1 [512]  (word layer0 h)
//   2560 : hw2 [512]  (word layer1 h -> decoder input)
//   3072 : g   [1]    (scalar gate)

__global__ __launch_bounds__(256) void k_char(
    int t,
    const int* __restrict__ x_char,
    const float* __restrict__ hch, const float* __restrict__ hcc,
    const float* __restrict__ char_emb,
    const float* __restrict__ cWih, const float* __restrict__ cWhh,
    const float* __restrict__ cbih, const float* __restrict__ cbhh,
    const float* __restrict__ word_emb, const int* __restrict__ x_word,
    const float* __restrict__ g_w, const float* __restrict__ g_b,
    float* __restrict__ ws)
{
    const int tid = threadIdx.x;
    const int bx = blockIdx.x;

    if (bx == 64){
        // extra block: scalar gate g, only at t==0
        if (t == 0){
            __shared__ float sw[4];
            const size_t wbase = (size_t)x_word[0] * 512;
            float p = g_w[2*tid]   * word_emb[wbase + 2*tid]
                    + g_w[2*tid+1] * word_emb[wbase + 2*tid+1];
            #pragma unroll
            for (int m = 32; m >= 1; m >>= 1) p += __shfl_xor(p, m, 64);
            if ((tid & 63) == 0) sw[tid >> 6] = p;
            __syncthreads();
            if (tid == 0){
                float gg = sw[0] + sw[1] + sw[2] + sw[3] + g_b[0];
                ws[3072] = fmaxf(gg, 0.0f);
            }
        }
        return;
    }

    __shared__ float sH1[256];   // layer1 hidden at t (input h for layer1; x for layer2)
    __shared__ float sH2[256];   // layer2 hidden at t-1
    __shared__ float sE[256];    // char embedding at t
    __shared__ float sg1[16], sg2[16];

    float* h1b = ws;
    float* h2b = ws + 512;
    float* c1  = ws + 1024;
    float* c2  = ws + 1280;

    sH1[tid] = (t == 0) ? hch[tid] : h1b[(t & 1)*256 + tid];
    if (t >= 1) sH2[tid] = (t == 1) ? hch[256 + tid] : h2b[((t-1) & 1)*256 + tid];
    if (t < 12) sE[tid] = char_emb[x_char[t]*256 + tid];
    __syncthreads();

    const int rg = tid >> 4;        // 0..15
    const int lane16 = tid & 15;
    const int gate = rg & 3;        // i,f,g,o
    const int uu = rg >> 2;         // 0..3
    const int u = (bx << 2) + uu;   // hidden unit 0..255
    const int row = (gate << 8) + u;

    float a1 = 0.f, a2 = 0.f;
    if (t < 12){
        const float4* wi = (const float4*)(cWih + (size_t)row*256) + lane16*4;
        const float4* wh = (const float4*)(cWhh + (size_t)row*256) + lane16*4;
        const float* xp = sE  + lane16*16;
        const float* hp = sH1 + lane16*16;
        #pragma unroll
        for (int j = 0; j < 4; ++j) a1 += dot4(wi[j], xp + 4*j) + dot4(wh[j], hp + 4*j);
    }
    if (t >= 1){
        const size_t r2 = (size_t)(1024 + row);
        const float4* wi = (const float4*)(cWih + r2*256) + lane16*4;
        const float4* wh = (const float4*)(cWhh + r2*256) + lane16*4;
        const float* xp = sH1 + lane16*16;
        const float* hp = sH2 + lane16*16;
        #pragma unroll
        for (int j = 0; j < 4; ++j) a2 += dot4(wi[j], xp + 4*j) + dot4(wh[j], hp + 4*j);
    }
    #pragma unroll
    for (int m = 8; m >= 1; m >>= 1){
        a1 += __shfl_xor(a1, m, 64);
        a2 += __shfl_xor(a2, m, 64);
    }
    if (lane16 == 0){
        if (t < 12) sg1[rg] = a1 + cbih[row]        + cbhh[row];
        if (t >= 1) sg2[rg] = a2 + cbih[1024 + row] + cbhh[1024 + row];
    }
    __syncthreads();

    if (tid < 4){
        if (t < 12){
            int uh = (bx << 2) + tid;
            float gi = sigf(sg1[tid*4+0]);
            float gf = sigf(sg1[tid*4+1]);
            float gg = tanhf_(sg1[tid*4+2]);
            float go = sigf(sg1[tid*4+3]);
            float cp = (t == 0) ? hcc[uh] : c1[uh];
            float c = gf * cp + gi * gg;
            c1[uh] = c;
            h1b[((t+1) & 1)*256 + uh] = go * tanhf_(c);
        }
    } else if (tid < 8){
        if (t >= 1){
            int q = tid - 4;
            int uh = (bx << 2) + q;
            float gi = sigf(sg2[q*4+0]);
            float gf = sigf(sg2[q*4+1]);
            float gg = tanhf_(sg2[q*4+2]);
            float go = sigf(sg2[q*4+3]);
            float cp = (t == 1) ? hcc[256 + uh] : c2[uh];
            float c = gf * cp + gi * gg;
            c2[uh] = c;
            h2b[(t & 1)*256 + uh] = go * tanhf_(c);
        }
    }
}

// char state outputs + xcw = cte @ c2
__global__ __launch_bounds__(256) void k_mix(
    const float* __restrict__ cte, float* __restrict__ ws,
    float* __restrict__ out)
{
    const int tid = threadIdx.x;
    const int bx = blockIdx.x;
    __shared__ float sC2[256];
    sC2[tid] = ws[1280 + tid];
    __syncthreads();

    if (tid < 4){
        int uh = (bx << 2) + tid;
        // final h1 is in buffer ((11+1)&1)=0; final h2 in buffer (12&1)=0
        out[52048 + uh]       = ws[uh];            // h_char_h layer0
        out[52048 + 256 + uh] = ws[512 + uh];      // h_char_h layer1
        out[52560 + uh]       = ws[1024 + uh];     // h_char_c layer0
        out[52560 + 256 + uh] = ws[1280 + uh];     // h_char_c layer1
    }
    const int rr = tid >> 5;        // 0..7
    const int lane32 = tid & 31;
    const int row = (bx << 3) + rr; // 0..511
    const float4* wp = (const float4*)(cte + (size_t)row*256) + lane32*2;
    float acc = dot4(wp[0], sC2 + lane32*8) + dot4(wp[1], sC2 + lane32*8 + 4);
    #pragma unroll
    for (int m = 16; m >= 1; m >>= 1) acc += __shfl_xor(acc, m, 64);
    if (lane32 == 0) ws[1536 + row] = acc;
}

// one word-LSTM layer (l = 0 or 1)
__global__ __launch_bounds__(256) void k_word(
    int l,
    const float* __restrict__ hwh, const float* __restrict__ hwc,
    const float* __restrict__ word_emb, const int* __restrict__ x_word,
    const float* __restrict__ wWih, const float* __restrict__ wWhh,
    const float* __restrict__ wbih, const float* __restrict__ wbhh,
    float* __restrict__ ws, float* __restrict__ out)
{
    const int tid = threadIdx.x;
    const int bx = blockIdx.x;
    __shared__ float sX[512];
    __shared__ float sg[32];

    if (l == 0){
        const size_t wbase = (size_t)x_word[0] * 512;
        float g = ws[3072];
        sX[2*tid]   = (1.0f - g) * word_emb[wbase + 2*tid]   + g * ws[1536 + 2*tid];
        sX[2*tid+1] = (1.0f - g) * word_emb[wbase + 2*tid+1] + g * ws[1536 + 2*tid+1];
    } else {
        sX[2*tid]   = ws[2048 + 2*tid];
        sX[2*tid+1] = ws[2048 + 2*tid+1];
    }
    __syncthreads();

    const int rg8 = tid >> 3;       // 0..31
    const int lane8 = tid & 7;
    const int gate = rg8 & 3;
    const int uu = rg8 >> 2;        // 0..7
    const int uw = (bx << 3) + uu;  // 0..511
    const int row = (gate << 9) + uw;
    const size_t rf = (size_t)(l*2048 + row);

    const float4* wi = (const float4*)(wWih + rf*512) + lane8*16;
    const float4* wh = (const float4*)(wWhh + rf*512) + lane8*16;
    const float4* hv = (const float4*)(hwh + l*512) + lane8*16;
    const float* xp = sX + lane8*64;
    float acc = 0.f;
    #pragma unroll
    for (int j = 0; j < 16; ++j){
        float4 h4 = hv[j];
        acc += dot4(wi[j], xp + 4*j);
        float4 w4 = wh[j];
        acc += w4.x*h4.x + w4.y*h4.y + w4.z*h4.z + w4.w*h4.w;
    }
    #pragma unroll
    for (int m = 4; m >= 1; m >>= 1) acc += __shfl_xor(acc, m, 64);
    if (lane8 == 0) sg[rg8] = acc + wbih[rf] + wbhh[rf];
    __syncthreads();

    if (tid < 8){
        int u2 = (bx << 3) + tid;
        float gi = sigf(sg[tid*4+0]);
        float gf = sigf(sg[tid*4+1]);
        float gg = tanhf_(sg[tid*4+2]);
        float go = sigf(sg[tid*4+3]);
        float c = gf * hwc[l*512 + u2] + gi * gg;
        float h = go * tanhf_(c);
        ws[2048 + l*512 + u2] = h;
        out[50000 + l*512 + u2] = h;   // h_word_h
        out[51024 + l*512 + u2] = c;   // h_word_c
    }
}

// decoder: y[r] = dec_W[r,:] . hw2 + dec_b[r]
__global__ __launch_bounds__(256) void k_dec(
    const float* __restrict__ dec_W, const float* __restrict__ dec_b,
    const float* __restrict__ h2, float* __restrict__ out)
{
    const int lane = threadIdx.x & 63;
    const int wid = (blockIdx.x * blockDim.x + threadIdx.x) >> 6;
    const int nw = (gridDim.x * blockDim.x) >> 6;
    const float4* hp = (const float4*)h2 + lane*2;
    float4 ha = hp[0], hb = hp[1];
    float hx0[4] = {ha.x, ha.y, ha.z, ha.w};
    float hx1[4] = {hb.x, hb.y, hb.z, hb.w};
    for (int r = wid; r < 50000; r += nw){
        const float4* wp = (const float4*)(dec_W + (size_t)r*512) + lane*2;
        float acc = dot4(wp[0], hx0) + dot4(wp[1], hx1);
        #pragma unroll
        for (int m = 32; m >= 1; m >>= 1) acc += __shfl_xor(acc, m, 64);
        if (lane == 0) out[r] = acc + dec_b[r];
    }
}

extern "C" void kernel_launch(void* const* d_in, const int* in_sizes, int n_in,
                              void* d_out, int out_size, void* d_ws, size_t ws_size,
                              hipStream_t stream)
{
    const int*   x_word   = (const int*)d_in[0];
    const int*   x_char   = (const int*)d_in[1];
    const float* hwh      = (const float*)d_in[2];
    const float* hwc      = (const float*)d_in[3];
    const float* hch      = (const float*)d_in[4];
    const float* hcc      = (const float*)d_in[5];
    const float* word_emb = (const float*)d_in[6];
    const float* wWih     = (const float*)d_in[7];
    const float* wWhh     = (const float*)d_in[8];
    const float* wbih     = (const float*)d_in[9];
    const float* wbhh     = (const float*)d_in[10];
    const float* dec_W    = (const float*)d_in[11];
    const float* dec_b    = (const float*)d_in[12];
    const float* char_emb = (const float*)d_in[13];
    const float* cWih     = (const float*)d_in[14];
    const float* cWhh     = (const float*)d_in[15];
    const float* cbih     = (const float*)d_in[16];
    const float* cbhh     = (const float*)d_in[17];
    const float* cte      = (const float*)d_in[18];
    const float* g_w      = (const float*)d_in[19];
    const float* g_b      = (const float*)d_in[20];

    float* ws = (float*)d_ws;
    float* out = (float*)d_out;

    for (int t = 0; t <= 12; ++t){
        hipLaunchKernelGGL(k_char, dim3(65), dim3(256), 0, stream,
            t, x_char, hch, hcc, char_emb, cWih, cWhh, cbih, cbhh,
            word_emb, x_word, g_w, g_b, ws);
    }
    hipLaunchKernelGGL(k_mix, dim3(64), dim3(256), 0, stream, cte, ws, out);
    hipLaunchKernelGGL(k_word, dim3(64), dim3(256), 0, stream,
        0, hwh, hwc, word_emb, x_word, wWih, wWhh, wbih, wbhh, ws, out);
    hipLaunchKernelGGL(k_word, dim3(64), dim3(256), 0, stream,
        1, hwh, hwc, word_emb, x_word, wWih, wWhh, wbih, wbhh, ws, out);
    hipLaunchKernelGGL(k_dec, dim3(625), dim3(256), 0, stream,
        dec_W, dec_b, ws + 2560, out);
}